// Round 2
// baseline (366.297 us; speedup 1.0000x reference)
//
#include <hip/hip_runtime.h>
#include <math.h>

#define TT 288
#define VV 512
#define NC 32
#define NB 4

// ws layout (floats):
//   XCS  : NB*NC*TT*VV  inclusive prefix sum of x over t
//   CV   : NB*TT*VV
//   IMP  : NB*TT
//   COEF : NB*8  (ew[i]/k_i for i<5)
static constexpr size_t XCS_OFF  = 0;
static constexpr size_t CV_OFF   = (size_t)NB * NC * TT * VV;      // 18,874,368
static constexpr size_t IMP_OFF  = CV_OFF + (size_t)NB * TT * VV;  // +589,824
static constexpr size_t COEF_OFF = IMP_OFF + (size_t)NB * TT;      // +1,152
static constexpr size_t WS_FLOATS_NEEDED = COEF_OFF + (size_t)NB * 8;
// total floats = 19,465,408 -> 77,861,632 bytes of ws

__global__ __launch_bounds__(256)
void prep_kernel(const float* __restrict__ flow,
                 const float* __restrict__ events,
                 const float* __restrict__ x,
                 const float* __restrict__ ef,
                 const float* __restrict__ w1, const float* __restrict__ b1,
                 const float* __restrict__ w2, const float* __restrict__ b2,
                 float* __restrict__ ws) {
  float* XCS  = ws + XCS_OFF;
  float* CVp  = ws + CV_OFF;
  float* IMP  = ws + IMP_OFF;
  float* COEF = ws + COEF_OFF;
  const int blk = blockIdx.x, thr = threadIdx.x;

  if (blk < 256) {
    // ---- prefix sum over t for one (b,c,v) column ----
    const int g   = blk * 256 + thr;           // [0, 65536)
    const int col = g >> 9;                    // b*32 + c
    const int v   = g & 511;
    const size_t base = (size_t)col * (TT * VV) + v;
    float acc = 0.f;
#pragma unroll 8
    for (int t = 0; t < TT; ++t) {
      acc += x[base + (size_t)t * VV];
      XCS[base + (size_t)t * VV] = acc;
    }
  } else if (blk < 264) {
    // ---- rolling CV for one (b,v) column ----
    const int j = (blk - 256) * 256 + thr;     // [0, 2048)
    const int b = j >> 9;
    const int v = j & 511;
    const size_t base = (size_t)b * (TT * VV) + v;
    float s = 0.f, s2 = 0.f;
    for (int t = 0; t < 59; ++t) {
      float f = flow[base + (size_t)t * VV];
      s += f; s2 += f * f;
      CVp[base + (size_t)t * VV] = 0.f;
    }
    for (int t = 59; t < TT; ++t) {
      float f = flow[base + (size_t)t * VV];
      s += f; s2 += f * f;
      float mean = s * (1.f / 60.f);
      float var  = (s2 - 60.f * mean * mean) * (1.f / 59.f);
      float sd   = sqrtf(fmaxf(var, 0.f));
      CVp[base + (size_t)t * VV] = sd / (mean + 1e-6f);
      float fo = flow[base + (size_t)(t - 59) * VV];
      s -= fo; s2 -= fo * fo;
    }
  } else {
    // ---- impact reverse scan (threads 0..3) + gate MLP (threads 4..7) ----
    if (thr < NB) {
      const int b = thr;
      const float r0 = expf(-1.f / 300.f), r1 = expf(-1.f / 600.f), r2 = expf(-1.f / 180.f);
      float c0 = 0.f, c1 = 0.f, c2 = 0.f;
      for (int t = TT - 1; t >= 0; --t) {
        const float* e = events + ((size_t)b * TT + t) * 3;
        c0 = e[0] + r0 * c0;
        c1 = e[1] + r1 * c1;
        c2 = e[2] + r2 * c2;
        IMP[b * TT + t] = 0.3f * c0 + 0.5f * c1 + 0.2f * c2;
      }
    } else if (thr >= 4 && thr < 8) {
      const int b = thr - 4;
      float h[32];
      for (int jj = 0; jj < 32; ++jj) {
        float a = b1[jj];
        for (int i = 0; i < 8; ++i) a += ef[b * 8 + i] * w1[i * 32 + jj];
        h[jj] = fmaxf(a, 0.f);
      }
      float lg[5];
      for (int k = 0; k < 5; ++k) {
        float a = b2[k];
        for (int jj = 0; jj < 32; ++jj) a += h[jj] * w2[jj * 5 + k];
        lg[k] = 1.f / (1.f + expf(-a));    // sigmoid
      }
      float m = lg[0];
      for (int k = 1; k < 5; ++k) m = fmaxf(m, lg[k]);
      float e5[5], es = 0.f;
      for (int k = 0; k < 5; ++k) { e5[k] = expf(lg[k] - m); es += e5[k]; }
      const float kk[5] = {3.f, 6.f, 12.f, 24.f, 48.f};
      for (int k = 0; k < 5; ++k) COEF[b * 8 + k] = (e5[k] / es) / kk[k];
    }
  }
}

__global__ __launch_bounds__(256)
void main_kernel(const float* __restrict__ fw, const float* __restrict__ fb,
                 const float* __restrict__ ws, float* __restrict__ out) {
  const float* XCS  = ws + XCS_OFF;
  const float* CVp  = ws + CV_OFF;
  const float* IMP  = ws + IMP_OFF;
  const float* COEF = ws + COEF_OFF;

  __shared__ float sA[32][32];   // sA[c][o] = fw[o][c] + (o==c)   (residual folded in)
  __shared__ float sB[32][32];   // sB[c][o] = fw[o][32+c]
  __shared__ float sFB[32];
  __shared__ float sCI[8];

  // XCD-chunked bijective swizzle: 1152 blocks = 8 * 144 -> consecutive t on one XCD
  const int raw = blockIdx.x;
  const int wg  = (raw & 7) * 144 + (raw >> 3);
  const int b   = wg / TT;
  const int t   = wg % TT;
  const int thr = threadIdx.x;

#pragma unroll
  for (int e = 0; e < 8; ++e) {
    int idx = thr + e * 256;          // [0, 2048)
    int mtx = idx >> 10;              // 0 -> A, 1 -> B
    int rem = idx & 1023;
    int o   = rem >> 5;
    int c   = rem & 31;
    float val = fw[o * 64 + mtx * 32 + c];
    if (mtx == 0) sA[c][o] = val + ((o == c) ? 1.f : 0.f);
    else          sB[c][o] = val;
  }
  if (thr < 32) sFB[thr] = fb[thr];
  if (thr < 5)  sCI[thr] = COEF[b * 8 + thr];
  __syncthreads();

  // pool-window prefix-tap offsets (uniform per block)
  const int DH[5] = {2, 3, 6, 12, 24};    // hi tap = min(t+DH,TT)-1
  const int DL[5] = {2, 4, 7, 13, 25};    // lo tap = t-DL (if >=0)
  int offH[5], offL[5];
  float mskL[5];
#pragma unroll
  for (int i = 0; i < 5; ++i) {
    int th = min(t + DH[i], TT) - 1;
    int tl = t - DL[i];
    offH[i] = th * VV;
    offL[i] = (tl >= 0 ? tl : 0) * VV;
    mskL[i] = (tl >= 0) ? 1.f : 0.f;
  }
  const int offT  = t * VV;
  const int offTm = (t > 0 ? t - 1 : 0) * VV;
  const float mskT = (t > 0) ? 1.f : 0.f;

  float ci[5];
#pragma unroll
  for (int i = 0; i < 5; ++i) ci[i] = sCI[i];
  const float ip = IMP[b * TT + t];

  const float* colbase = XCS + (size_t)b * NC * TT * VV + thr;  // point0: +0, point1: +256

  float acc0[32], acc1[32];
#pragma unroll
  for (int o = 0; o < 32; ++o) { acc0[o] = 0.f; acc1[o] = 0.f; }

#pragma unroll 2
  for (int c = 0; c < 32; ++c) {
    const float* cb = colbase + (size_t)c * (TT * VV);
    // point 0 (v = thr), point 1 (v = thr + 256)
    float Xt0 = cb[offT],        Xt1 = cb[offT + 256];
    float Xm0 = cb[offTm],       Xm1 = cb[offTm + 256];
    float xv0 = Xt0 - mskT * Xm0;
    float xv1 = Xt1 - mskT * Xm1;
    float comb0 = 0.f, comb1 = 0.f;
#pragma unroll
    for (int i = 0; i < 5; ++i) {
      float H0 = cb[offH[i]],       H1 = cb[offH[i] + 256];
      float L0 = cb[offL[i]],       L1 = cb[offL[i] + 256];
      comb0 += ci[i] * (H0 - mskL[i] * L0);
      comb1 += ci[i] * (H1 - mskL[i] * L1);
    }
    const float* rA = &sA[c][0];
    const float* rB = &sB[c][0];
#pragma unroll
    for (int o = 0; o < 32; o += 4) {
      float4 a4 = *(const float4*)(rA + o);
      float4 b4 = *(const float4*)(rB + o);
      acc0[o + 0] += a4.x * xv0 + b4.x * comb0;
      acc0[o + 1] += a4.y * xv0 + b4.y * comb0;
      acc0[o + 2] += a4.z * xv0 + b4.z * comb0;
      acc0[o + 3] += a4.w * xv0 + b4.w * comb0;
      acc1[o + 0] += a4.x * xv1 + b4.x * comb1;
      acc1[o + 1] += a4.y * xv1 + b4.y * comb1;
      acc1[o + 2] += a4.z * xv1 + b4.z * comb1;
      acc1[o + 3] += a4.w * xv1 + b4.w * comb1;
    }
  }

  const float mcv0 = 1.f + CVp[((size_t)b * TT + t) * VV + thr];
  const float mcv1 = 1.f + CVp[((size_t)b * TT + t) * VV + thr + 256];
#pragma unroll
  for (int o = 0; o < 32; ++o) {
    size_t ob = (((size_t)b * NC + o) * TT + t) * VV + thr;
    out[ob]       = (acc0[o] + sFB[o]) * mcv0 + ip;
    out[ob + 256] = (acc1[o] + sFB[o]) * mcv1 + ip;
  }
}

extern "C" void kernel_launch(void* const* d_in, const int* in_sizes, int n_in,
                              void* d_out, int out_size, void* d_ws, size_t ws_size,
                              hipStream_t stream) {
  // Guard: if the harness workspace is smaller than we need, bail out cleanly
  // (fails absmax with a zeroed-out output instead of corrupting device memory).
  if (ws_size < WS_FLOATS_NEEDED * sizeof(float)) return;

  const float* flow = (const float*)d_in[0];
  const float* ev   = (const float*)d_in[1];
  const float* x    = (const float*)d_in[2];
  const float* ef   = (const float*)d_in[3];
  const float* w1   = (const float*)d_in[4];
  const float* b1   = (const float*)d_in[5];
  const float* w2   = (const float*)d_in[6];
  const float* b2   = (const float*)d_in[7];
  const float* fw   = (const float*)d_in[8];
  const float* fb   = (const float*)d_in[9];
  float* ws  = (float*)d_ws;
  float* out = (float*)d_out;

  prep_kernel<<<265, 256, 0, stream>>>(flow, ev, x, ef, w1, b1, w2, b2, ws);
  main_kernel<<<NB * TT, 256, 0, stream>>>(fw, fb, ws, out);
}